// Round 2
// baseline (129.165 us; speedup 1.0000x reference)
//
#include <hip/hip_runtime.h>

#define GQ 8192   // bs(32) * Gn(256)

// One wave per group. Lane l owns channels (l, l+64) of the [S=16, C=128]
// feature tile; columns are loaded straight from global (no LDS staging).
// Label/index logic is wave-uniform -> scalar pipe. Cross-channel pair
// reduction goes through a 9x132 M matrix in LDS (5.1 KB total).
__global__ __launch_bounds__(64, 6) void group_loss_kernel(
    const int*   __restrict__ labs,   // [G*16]
    const float* __restrict__ feats,  // [32,128,256,16]
    const int*   __restrict__ idxs,   // [G*16]
    const float* __restrict__ ctx,    // [128]
    float* __restrict__ ws0, float* __restrict__ ws1)
{
    __shared__ float MM[9 * 132 + 4];   // rows padded to 132 floats (bank spread)
    __shared__ float SIMM[81];

    const int l   = threadIdx.x;
    const int blk = blockIdx.x;
    // XCD swizzle: contiguous 1024-group chunk per XCD; adjacent gn share L2 lines
    const int g  = ((blk & 7) << 10) | (blk >> 3);
    const int b  = g >> 8;
    const int gn = g & 255;
    const long fbase = (long)b * (128 * 256 * 16) + (long)gn * 16;

    // ---- issue global column loads early (lane's 2 channels, 16 floats each)
    const float* gp0 = feats + fbase + (long)l * 4096;
    const float* gp1 = gp0 + 64 * 4096;
    float4 A[4], B[4];
    #pragma unroll
    for (int q = 0; q < 4; ++q) A[q] = *(const float4*)(gp0 + q * 4);
    #pragma unroll
    for (int q = 0; q < 4; ++q) B[q] = *(const float4*)(gp1 + q * 4);
    const float cx0 = ctx[l], cx1 = ctx[l + 64];

    // ---- wave-uniform label/index logic (scalar pipe, overlaps load latency)
    int lab_u[16], idx_u[16];
    #pragma unroll
    for (int s = 0; s < 16; ++s) {
        lab_u[s] = labs[g * 16 + s];
        idx_u[s] = idxs[g * 16 + s];
    }
    // u = number of distinct seed-index values
    int u = 1;
    #pragma unroll
    for (int s = 1; s < 16; ++s) {
        bool dup = false;
        #pragma unroll
        for (int j = 0; j < s; ++j) dup = dup || (idx_u[j] == idx_u[s]);
        u += dup ? 0 : 1;
    }
    // bucket r=0 is label -1 (bg); r=1..8 are fg labels 0..7
    unsigned memb[9]; int cnt[9];
    #pragma unroll
    for (int r = 0; r < 9; ++r) {
        unsigned m = 0; int c = 0;
        #pragma unroll
        for (int s = 0; s < 16; ++s) {
            if (s < u && lab_u[s] == r - 1) { m |= (1u << s); ++c; }
        }
        memb[r] = m; cnt[r] = c;
    }
    const bool has_bg = cnt[0] > 0;
    int fg_count = 0, pm = 0;
    #pragma unroll
    for (int r = 1; r < 9; ++r) {
        if (cnt[r] > 0) { ++fg_count; pm |= 1 << r; }
    }

    // ---- per-bucket means for this lane's 2 channels (uniform-branch adds)
    float m0[9], m1[9];
    #pragma unroll
    for (int r = 0; r < 9; ++r) {
        float a = 0.0f, bb = 0.0f;
        const unsigned m = memb[r];
        #pragma unroll
        for (int q = 0; q < 4; ++q) {
            if (m & (1u << (4 * q + 0))) { a += A[q].x; bb += B[q].x; }
            if (m & (1u << (4 * q + 1))) { a += A[q].y; bb += B[q].y; }
            if (m & (1u << (4 * q + 2))) { a += A[q].z; bb += B[q].z; }
            if (m & (1u << (4 * q + 3))) { a += A[q].w; bb += B[q].w; }
        }
        const float invc = 1.0f / (float)(cnt[r] > 0 ? cnt[r] : 1);
        m0[r] = a * invc;
        m1[r] = bb * invc;
    }
    if (!has_bg) { m0[0] = cx0; m1[0] = cx1; }   // row 0 = context_compen

    // ---- M -> LDS (2-way bank aliasing = free)
    #pragma unroll
    for (int r = 0; r < 9; ++r) {
        MM[r * 132 + l]      = m0[r];
        MM[r * 132 + 64 + l] = m1[r];
    }
    __syncthreads();

    // ---- 44 pairs (i,j), 1<=i<=8, 0<=j<=i : lane p dots rows i,j over 128 ch
    float simv = 0.0f; int pi = 0, pj = 0;
    if (l < 44) {
        pi = (int)((sqrtf(8.0f * (float)l + 9.0f) - 1.0f) * 0.5f);
        pj = l - (pi * (pi + 1) / 2 - 1);
        const float* Ri = MM + pi * 132;
        const float* Rj = MM + pj * 132;
        float acc = 0.0f;
        #pragma unroll
        for (int q = 0; q < 32; ++q) {
            float4 x = *(const float4*)(Ri + 4 * q);
            float4 y = *(const float4*)(Rj + 4 * q);
            acc += x.x * y.x + x.y * y.y + x.z * y.z + x.w * y.w;
        }
        simv = acc * 5.0f;                        // 1/T
    }
    if (l < 44) {
        SIMM[pi * 9 + pj] = simv;
        if (pi != pj) SIMM[pj * 9 + pi] = simv;
    }
    __syncthreads();

    // ---- masked logsumexp per present fg row (lane r = row r)
    float li_val = 0.0f;
    if (l >= 1 && l < 9 && ((pm >> l) & 1)) {
        float srow[9];
        #pragma unroll
        for (int j = 0; j < 9; ++j) srow[j] = SIMM[l * 9 + j];
        float vmax = srow[0];                     // col 0 (bg/ctx) always valid
        #pragma unroll
        for (int j = 1; j < 9; ++j)
            if ((pm >> j) & 1) vmax = fmaxf(vmax, srow[j]);
        float se = __expf(srow[0] - vmax);
        #pragma unroll
        for (int j = 1; j < 9; ++j)
            if ((pm >> j) & 1) se += __expf(srow[j] - vmax);
        li_val = vmax + __logf(se) - srow[l];
    }

    // ---- sum li over lanes 1..8 via shuffles; write per-group results
    float ssum = li_val;
    #pragma unroll
    for (int off = 8; off >= 1; off >>= 1) ssum += __shfl_down(ssum, off);
    if (l == 0) {
        ws0[g] = ssum / (float)(fg_count > 0 ? fg_count : 1);  // gl*gv
        ws1[g] = (fg_count > 0) ? 1.0f : 0.0f;                 // gv
    }
}

// Deterministic 8192 -> 1 reduction
__global__ __launch_bounds__(256) void reduce_kernel(
    const float* __restrict__ ws0, const float* __restrict__ ws1,
    float* __restrict__ out)
{
    __shared__ float sa[256], sb[256];
    const int t = threadIdx.x;
    float a = 0.0f, b2 = 0.0f;
    for (int g = t; g < GQ; g += 256) { a += ws0[g]; b2 += ws1[g]; }
    sa[t] = a; sb[t] = b2;
    __syncthreads();
    for (int off = 128; off > 0; off >>= 1) {
        if (t < off) { sa[t] += sa[t + off]; sb[t] += sb[t + off]; }
        __syncthreads();
    }
    if (t == 0) out[0] = 0.1f * (sa[0] / sb[0]);
}

extern "C" void kernel_launch(void* const* d_in, const int* in_sizes, int n_in,
                              void* d_out, int out_size, void* d_ws, size_t ws_size,
                              hipStream_t stream) {
    const int*   labs  = (const int*)d_in[0];    // proposal_instance_mask
    const float* feats = (const float*)d_in[1];  // grouped_features
    const int*   idxs  = (const int*)d_in[2];    // grouped_indices
    const float* ctx   = (const float*)d_in[3];  // context_compen
    float* out = (float*)d_out;
    float* ws0 = (float*)d_ws;
    float* ws1 = ws0 + GQ;

    group_loss_kernel<<<GQ, 64, 0, stream>>>(labs, feats, idxs, ctx, ws0, ws1);
    reduce_kernel<<<1, 256, 0, stream>>>(ws0, ws1, out);
}

// Round 3
// 128.588 us; speedup vs baseline: 1.0045x; 1.0045x over previous
//
#include <hip/hip_runtime.h>

#define GQ 8192   // bs(32) * Gn(256)

// 4 waves per block, one group per wave (independent; per-wave LDS slice).
// Lane l owns channels (l, l+64); columns loaded straight from global.
// Label/index logic is wave-uniform -> scalar pipe.
#define WPB 4                 // waves per block
#define MROW 132              // M row stride (floats): 128 + 4 pad (bank spread)
#define WSLICE (9 * MROW + 81 + 11)   // per-wave LDS floats = 1280

__global__ __launch_bounds__(64 * WPB, 2) void group_loss_kernel(
    const int*   __restrict__ labs,   // [G*16]
    const float* __restrict__ feats,  // [32,128,256,16]
    const int*   __restrict__ idxs,   // [G*16]
    const float* __restrict__ ctx,    // [128]
    float2* __restrict__ ws)          // [G] {gl*gv, gv}
{
    __shared__ float SH[WPB * WSLICE];    // 20480 B -> 7 blocks/CU = 28 waves

    const int l = threadIdx.x & 63;
    const int w = threadIdx.x >> 6;
    float* MM   = SH + w * WSLICE;        // 9 x 132
    float* SIMM = MM + 9 * MROW;          // 81

    const int flat = blockIdx.x * WPB + w;
    // XCD swizzle: contiguous 1024-group chunk per XCD
    const int g  = ((flat & 7) << 10) | (flat >> 3);
    const int b  = g >> 8;
    const int gn = g & 255;
    const long fbase = (long)b * (128 * 256 * 16) + (long)gn * 16;

    // ---- issue global column loads early (lane's 2 channels, 16 floats each)
    const float* gp0 = feats + fbase + (long)l * 4096;
    const float* gp1 = gp0 + 64 * 4096;
    float4 A[4], B[4];
    #pragma unroll
    for (int q = 0; q < 4; ++q) A[q] = *(const float4*)(gp0 + q * 4);
    #pragma unroll
    for (int q = 0; q < 4; ++q) B[q] = *(const float4*)(gp1 + q * 4);
    const float cx0 = ctx[l], cx1 = ctx[l + 64];

    // ---- wave-uniform label/index logic (scalar pipe, overlaps load latency)
    int lab_u[16], idx_u[16];
    #pragma unroll
    for (int s = 0; s < 16; ++s) {
        lab_u[s] = labs[g * 16 + s];
        idx_u[s] = idxs[g * 16 + s];
    }
    int u = 1;
    #pragma unroll
    for (int s = 1; s < 16; ++s) {
        bool dup = false;
        #pragma unroll
        for (int j = 0; j < s; ++j) dup = dup || (idx_u[j] == idx_u[s]);
        u += dup ? 0 : 1;
    }
    // bucket r=0 is label -1 (bg); r=1..8 are fg labels 0..7
    unsigned memb[9]; int cnt[9];
    #pragma unroll
    for (int r = 0; r < 9; ++r) {
        unsigned m = 0; int c = 0;
        #pragma unroll
        for (int s = 0; s < 16; ++s) {
            if (s < u && lab_u[s] == r - 1) { m |= (1u << s); ++c; }
        }
        memb[r] = m; cnt[r] = c;
    }
    const bool has_bg = cnt[0] > 0;
    int fg_count = 0, pm = 0;
    #pragma unroll
    for (int r = 1; r < 9; ++r) {
        if (cnt[r] > 0) { ++fg_count; pm |= 1 << r; }
    }

    // ---- per-bucket means for this lane's 2 channels (uniform-branch adds)
    float m0[9], m1[9];
    #pragma unroll
    for (int r = 0; r < 9; ++r) {
        float a = 0.0f, bb = 0.0f;
        const unsigned m = memb[r];
        #pragma unroll
        for (int q = 0; q < 4; ++q) {
            if (m & (1u << (4 * q + 0))) { a += A[q].x; bb += B[q].x; }
            if (m & (1u << (4 * q + 1))) { a += A[q].y; bb += B[q].y; }
            if (m & (1u << (4 * q + 2))) { a += A[q].z; bb += B[q].z; }
            if (m & (1u << (4 * q + 3))) { a += A[q].w; bb += B[q].w; }
        }
        const float invc = 1.0f / (float)(cnt[r] > 0 ? cnt[r] : 1);
        m0[r] = a * invc;
        m1[r] = bb * invc;
    }
    if (!has_bg) { m0[0] = cx0; m1[0] = cx1; }   // row 0 = context_compen

    // ---- M -> LDS (2-way bank aliasing = free)
    #pragma unroll
    for (int r = 0; r < 9; ++r) {
        MM[r * MROW + l]      = m0[r];
        MM[r * MROW + 64 + l] = m1[r];
    }
    __syncthreads();

    // ---- 44 pairs (i,j), 1<=i<=8, 0<=j<=i : lane p dots rows i,j over 128 ch
    float simv = 0.0f; int pi = 0, pj = 0;
    if (l < 44) {
        pi = (int)((sqrtf(8.0f * (float)l + 9.0f) - 1.0f) * 0.5f);
        pj = l - (pi * (pi + 1) / 2 - 1);
        const float* Ri = MM + pi * MROW;
        const float* Rj = MM + pj * MROW;
        float acc = 0.0f;
        #pragma unroll
        for (int q = 0; q < 32; ++q) {
            float4 x = *(const float4*)(Ri + 4 * q);
            float4 y = *(const float4*)(Rj + 4 * q);
            acc += x.x * y.x + x.y * y.y + x.z * y.z + x.w * y.w;
        }
        simv = acc * 5.0f;                        // 1/T
    }
    if (l < 44) {
        SIMM[pi * 9 + pj] = simv;
        if (pi != pj) SIMM[pj * 9 + pi] = simv;
    }
    __syncthreads();

    // ---- masked logsumexp per present fg row (lane r = row r)
    float li_val = 0.0f;
    if (l >= 1 && l < 9 && ((pm >> l) & 1)) {
        float srow[9];
        #pragma unroll
        for (int j = 0; j < 9; ++j) srow[j] = SIMM[l * 9 + j];
        float vmax = srow[0];                     // col 0 (bg/ctx) always valid
        #pragma unroll
        for (int j = 1; j < 9; ++j)
            if ((pm >> j) & 1) vmax = fmaxf(vmax, srow[j]);
        float se = __expf(srow[0] - vmax);
        #pragma unroll
        for (int j = 1; j < 9; ++j)
            if ((pm >> j) & 1) se += __expf(srow[j] - vmax);
        li_val = vmax + __logf(se) - srow[l];
    }

    // ---- sum li over lanes 1..8 via shuffles; single float2 store
    float ssum = li_val;
    #pragma unroll
    for (int off = 8; off >= 1; off >>= 1) ssum += __shfl_down(ssum, off);
    if (l == 0) {
        float2 r;
        r.x = ssum / (float)(fg_count > 0 ? fg_count : 1);   // gl*gv
        r.y = (fg_count > 0) ? 1.0f : 0.0f;                  // gv
        ws[g] = r;
    }
}

// Deterministic 8192 -> 1 reduction
__global__ __launch_bounds__(1024) void reduce_kernel(
    const float2* __restrict__ ws, float* __restrict__ out)
{
    __shared__ float sa[1024], sb[1024];
    const int t = threadIdx.x;
    float a = 0.0f, b2 = 0.0f;
    for (int g = t; g < GQ; g += 1024) {
        float2 v = ws[g];
        a += v.x; b2 += v.y;
    }
    sa[t] = a; sb[t] = b2;
    __syncthreads();
    for (int off = 512; off > 0; off >>= 1) {
        if (t < off) { sa[t] += sa[t + off]; sb[t] += sb[t + off]; }
        __syncthreads();
    }
    if (t == 0) out[0] = 0.1f * (sa[0] / sb[0]);
}

extern "C" void kernel_launch(void* const* d_in, const int* in_sizes, int n_in,
                              void* d_out, int out_size, void* d_ws, size_t ws_size,
                              hipStream_t stream) {
    const int*   labs  = (const int*)d_in[0];    // proposal_instance_mask
    const float* feats = (const float*)d_in[1];  // grouped_features
    const int*   idxs  = (const int*)d_in[2];    // grouped_indices
    const float* ctx   = (const float*)d_in[3];  // context_compen
    float* out = (float*)d_out;
    float2* ws = (float2*)d_ws;

    group_loss_kernel<<<GQ / WPB, 64 * WPB, 0, stream>>>(labs, feats, idxs, ctx, ws);
    reduce_kernel<<<1, 1024, 0, stream>>>(ws, out);
}

// Round 4
// 123.703 us; speedup vs baseline: 1.0442x; 1.0395x over previous
//
#include <hip/hip_runtime.h>

#define GQ   8192            // bs(32) * Gn(256)
#define WPB  4               // waves per block; block covers 4 consecutive groups
#define FROW 132             // LDS row stride (floats) for F[s][c] and M[r][c]
#define SLICE 2144           // per-wave LDS floats: F 16x132=2112, aliased by M(9x132)+SIMM(81)

// One wave per group; 4 consecutive groups per block so both 64B halves of each
// 128B feature line are consumed in the same CU (MSHR merge). Global loads use
// the fully-consumed-line shape: lane (c=16i+(l>>2), q=l&3), staged to LDS
// F[s][c] (stride 132 -> all phases <=2-way bank aliasing = free).
__global__ __launch_bounds__(64 * WPB, 4) void group_loss_kernel(
    const int*   __restrict__ labs,   // [G*16]
    const float* __restrict__ feats,  // [32,128,256,16]
    const int*   __restrict__ idxs,   // [G*16]
    const float* __restrict__ ctx,    // [128]
    float2* __restrict__ ws)          // [G] {gl*gv, gv}
{
    __shared__ float SH[WPB * SLICE];           // 34304 B -> 4 blocks/CU

    const int l  = threadIdx.x & 63;
    const int wu = __builtin_amdgcn_readfirstlane(threadIdx.x >> 6);
    float* F    = SH + wu * SLICE;              // 16 x 132 (s-major)
    float* MM   = F;                            // alias: M 9 x 132 (written after F consumed)
    float* SIMM = F + 9 * FROW;                 // 81 floats

    const int blk = blockIdx.x;
    // XCD blk&7 owns contiguous groups [x*1024, x*1024+1024); waves take g..g+3
    const int g  = ((blk & 7) << 10) | ((blk >> 3) << 2) | wu;
    const int b  = g >> 8;
    const int gn = g & 255;
    const long fbase = (long)b * (128 * 256 * 16) + (long)gn * 16;

    // ---- global loads first (8 in flight): lane covers (c=16i+(l>>2), s=4q..4q+3)
    const float* gp = feats + fbase + (long)((l >> 2) * 4096 + (l & 3) * 4);
    float4 v[8];
    #pragma unroll
    for (int i = 0; i < 8; ++i) v[i] = *(const float4*)(gp + (long)i * 65536);

    // ---- wave-uniform label/index logic on the scalar pipe ------------------
    int lab_u[16], idx_u[16];
    #pragma unroll
    for (int s = 0; s < 16; ++s) {
        lab_u[s] = labs[g * 16 + s];
        idx_u[s] = idxs[g * 16 + s];
    }
    int u = 1;
    #pragma unroll
    for (int s = 1; s < 16; ++s) {
        bool dup = false;
        #pragma unroll
        for (int j = 0; j < s; ++j) dup = dup || (idx_u[j] == idx_u[s]);
        u += dup ? 0 : 1;
    }
    unsigned memb[9]; int cnt[9];
    #pragma unroll
    for (int r = 0; r < 9; ++r) {
        unsigned m = 0; int c = 0;
        #pragma unroll
        for (int s = 0; s < 16; ++s) {
            if (s < u && lab_u[s] == r - 1) { m |= (1u << s); ++c; }
        }
        memb[r] = m; cnt[r] = c;
    }
    const bool has_bg = cnt[0] > 0;
    int fg_count = 0, pm = 0;
    #pragma unroll
    for (int r = 1; r < 9; ++r) {
        if (cnt[r] > 0) { ++fg_count; pm |= 1 << r; }
    }

    // ---- stage F[s][c]: 4 b32 writes per loaded float4 (2-way = free) ------
    {
        const int c = 16 * 0 + (l >> 2);     // channel low bits; +16 per i below
        const int s0 = 4 * (l & 3);
        #pragma unroll
        for (int i = 0; i < 8; ++i) {
            const int cc = c + 16 * i;
            F[(s0 + 0) * FROW + cc] = v[i].x;
            F[(s0 + 1) * FROW + cc] = v[i].y;
            F[(s0 + 2) * FROW + cc] = v[i].z;
            F[(s0 + 3) * FROW + cc] = v[i].w;
        }
    }
    __syncthreads();

    // ---- lane's two channel columns (c0=l, c1=l+64): b32 reads, 2-way free -
    float fa[16], fb[16];
    #pragma unroll
    for (int s = 0; s < 16; ++s) {
        fa[s] = F[s * FROW + l];
        fb[s] = F[s * FROW + 64 + l];
    }
    const float cx0 = ctx[l], cx1 = ctx[l + 64];

    // ---- per-bucket means (wave-uniform membership -> scalar branches) -----
    float m0[9], m1[9];
    #pragma unroll
    for (int r = 0; r < 9; ++r) {
        float a = 0.0f, bb = 0.0f;
        const unsigned m = memb[r];
        #pragma unroll
        for (int s = 0; s < 16; ++s) {
            if (m & (1u << s)) { a += fa[s]; bb += fb[s]; }
        }
        const float invc = 1.0f / (float)(cnt[r] > 0 ? cnt[r] : 1);
        m0[r] = a * invc;
        m1[r] = bb * invc;
    }
    if (!has_bg) { m0[0] = cx0; m1[0] = cx1; }   // row 0 = context_compen

    __syncthreads();                             // F fully consumed; M may alias

    // ---- M -> LDS ----------------------------------------------------------
    #pragma unroll
    for (int r = 0; r < 9; ++r) {
        MM[r * FROW + l]      = m0[r];
        MM[r * FROW + 64 + l] = m1[r];
    }
    __syncthreads();

    // ---- 44 pairs (i,j), 1<=i<=8, 0<=j<=i: lane p dots rows i,j over 128 ch
    float simv = 0.0f; int pi = 0, pj = 0;
    if (l < 44) {
        pi = (int)((sqrtf(8.0f * (float)l + 9.0f) - 1.0f) * 0.5f);
        pj = l - (pi * (pi + 1) / 2 - 1);
        const float* Ri = MM + pi * FROW;
        const float* Rj = MM + pj * FROW;
        float acc = 0.0f;
        #pragma unroll
        for (int q = 0; q < 32; ++q) {
            float4 x = *(const float4*)(Ri + 4 * q);
            float4 y = *(const float4*)(Rj + 4 * q);
            acc += x.x * y.x + x.y * y.y + x.z * y.z + x.w * y.w;
        }
        simv = acc * 5.0f;                        // 1/T
    }
    if (l < 44) {
        SIMM[pi * 9 + pj] = simv;
        if (pi != pj) SIMM[pj * 9 + pi] = simv;
    }
    __syncthreads();

    // ---- masked logsumexp per present fg row (lane r = row r) --------------
    float li_val = 0.0f;
    if (l >= 1 && l < 9 && ((pm >> l) & 1)) {
        float srow[9];
        #pragma unroll
        for (int j = 0; j < 9; ++j) srow[j] = SIMM[l * 9 + j];
        float vmax = srow[0];                     // col 0 (bg/ctx) always valid
        #pragma unroll
        for (int j = 1; j < 9; ++j)
            if ((pm >> j) & 1) vmax = fmaxf(vmax, srow[j]);
        float se = __expf(srow[0] - vmax);
        #pragma unroll
        for (int j = 1; j < 9; ++j)
            if ((pm >> j) & 1) se += __expf(srow[j] - vmax);
        li_val = vmax + __logf(se) - srow[l];
    }

    // ---- sum li over lanes 1..8; single float2 store -----------------------
    float ssum = li_val;
    #pragma unroll
    for (int off = 8; off >= 1; off >>= 1) ssum += __shfl_down(ssum, off);
    if (l == 0) {
        float2 r;
        r.x = ssum / (float)(fg_count > 0 ? fg_count : 1);   // gl*gv
        r.y = (fg_count > 0) ? 1.0f : 0.0f;                  // gv
        ws[g] = r;
    }
}

// Deterministic 8192 -> 1 reduction
__global__ __launch_bounds__(1024) void reduce_kernel(
    const float2* __restrict__ ws, float* __restrict__ out)
{
    __shared__ float sa[1024], sb[1024];
    const int t = threadIdx.x;
    float a = 0.0f, b2 = 0.0f;
    for (int g = t; g < GQ; g += 1024) {
        float2 v = ws[g];
        a += v.x; b2 += v.y;
    }
    sa[t] = a; sb[t] = b2;
    __syncthreads();
    for (int off = 512; off > 0; off >>= 1) {
        if (t < off) { sa[t] += sa[t + off]; sb[t] += sb[t + off]; }
        __syncthreads();
    }
    if (t == 0) out[0] = 0.1f * (sa[0] / sb[0]);
}

extern "C" void kernel_launch(void* const* d_in, const int* in_sizes, int n_in,
                              void* d_out, int out_size, void* d_ws, size_t ws_size,
                              hipStream_t stream) {
    const int*   labs  = (const int*)d_in[0];    // proposal_instance_mask
    const float* feats = (const float*)d_in[1];  // grouped_features
    const int*   idxs  = (const int*)d_in[2];    // grouped_indices
    const float* ctx   = (const float*)d_in[3];  // context_compen
    float* out = (float*)d_out;
    float2* ws = (float2*)d_ws;

    group_loss_kernel<<<GQ / WPB, 64 * WPB, 0, stream>>>(labs, feats, idxs, ctx, ws);
    reduce_kernel<<<1, 1024, 0, stream>>>(ws, out);
}

// Round 5
// 112.045 us; speedup vs baseline: 1.1528x; 1.1040x over previous
//
#include <hip/hip_runtime.h>

#define GQ   8192            // bs(32) * Gn(256)
#define WPB  2               // waves per block (2 consecutive groups share 128B lines)
#define MROW 132             // M row stride in floats (128 + 4: rows shift 4 banks)
#define SLICE 1280           // per-wave LDS floats: M 9x132=1188 + SIMM 81 + pad

// One wave per group, short program, minimal serial chains:
//  - label/index logic via shuffles + ballots (no scalar pipeline, no LDS)
//  - bucket means via 16 uniform switch dispatches (readlane -> scalar branch)
//  - lane l owns channels (l, l+64), loaded straight to registers
//  - only 2 block barriers (M exchange, SIMM exchange)
__global__ __launch_bounds__(64 * WPB, 6) void group_loss_kernel(
    const int*   __restrict__ labs,   // [G*16]
    const float* __restrict__ feats,  // [32,128,256,16]
    const int*   __restrict__ idxs,   // [G*16]
    const float* __restrict__ ctx,    // [128]
    float2* __restrict__ ws)          // [G] {gl*gv, gv}
{
    __shared__ float SH[WPB * SLICE];           // 10240 B -> LDS allows 16 blocks/CU

    const int l  = threadIdx.x & 63;
    const int wu = threadIdx.x >> 6;
    float* MM   = SH + wu * SLICE;              // 9 x 132
    float* SIMM = MM + 9 * MROW;                // 81

    const int blk = blockIdx.x;
    // XCD blk&7 owns contiguous groups [x*1024, (x+1)*1024); block = gn pair
    const int g  = ((blk & 7) << 10) | ((blk >> 3) << 1) | wu;
    const int b  = g >> 8;
    const int gn = g & 255;
    const long fbase = (long)b * (128 * 256 * 16) + (long)gn * 16;

    // ---- feature columns straight to registers (lane l -> channels l, l+64)
    const float* gp0 = feats + fbase + (long)l * 4096;
    const float* gp1 = gp0 + 64 * 4096;
    float4 A[4], B[4];
    #pragma unroll
    for (int q = 0; q < 4; ++q) A[q] = *(const float4*)(gp0 + q * 4);
    #pragma unroll
    for (int q = 0; q < 4; ++q) B[q] = *(const float4*)(gp1 + q * 4);
    const float cx0 = ctx[l], cx1 = ctx[l + 64];
    float fa[16], fb[16];
    #pragma unroll
    for (int q = 0; q < 4; ++q) {
        fa[4*q+0] = A[q].x; fa[4*q+1] = A[q].y; fa[4*q+2] = A[q].z; fa[4*q+3] = A[q].w;
        fb[4*q+0] = B[q].x; fb[4*q+1] = B[q].y; fb[4*q+2] = B[q].z; fb[4*q+3] = B[q].w;
    }

    // ---- label/index logic: lanes 0..15 hold sample s=l ---------------------
    int myidx = -1, mylab = -2;
    if (l < 16) { myidx = idxs[g * 16 + l]; mylab = labs[g * 16 + l]; }

    // u = count of distinct seed indices (first-occurrence positions)
    bool dup = false;
    #pragma unroll
    for (int j = 0; j < 15; ++j) {
        const int vj = __shfl(myidx, j);
        dup = dup || ((l > j) && (myidx == vj));
    }
    const int u = __popcll(__ballot((l < 16) && !dup));

    const bool valid = l < u;                   // u<=16, lanes>=16 invalid
    const int bid = valid ? (mylab + 1) : 255;  // bucket 0 = bg(-1), 1..8 = fg

    unsigned long long memb[9]; int cnt[9];
    #pragma unroll
    for (int r = 0; r < 9; ++r) {
        memb[r] = __ballot(bid == r);
        cnt[r]  = __popcll(memb[r]);
    }
    const bool has_bg = cnt[0] > 0;
    int fg_count = 0, pm = 0;
    #pragma unroll
    for (int r = 1; r < 9; ++r)
        if (cnt[r] > 0) { ++fg_count; pm |= 1 << r; }

    // ---- bucket sums: 16 uniform dispatches (readlane -> scalar switch) ----
    float m0[9] = {0,0,0,0,0,0,0,0,0};
    float m1[9] = {0,0,0,0,0,0,0,0,0};
    #pragma unroll
    for (int s = 0; s < 16; ++s) {
        if (s < u) {                                        // uniform compare
            const int bs = __builtin_amdgcn_readlane(bid, s); // uniform 0..8
            switch (bs) {
                case 0: m0[0] += fa[s]; m1[0] += fb[s]; break;
                case 1: m0[1] += fa[s]; m1[1] += fb[s]; break;
                case 2: m0[2] += fa[s]; m1[2] += fb[s]; break;
                case 3: m0[3] += fa[s]; m1[3] += fb[s]; break;
                case 4: m0[4] += fa[s]; m1[4] += fb[s]; break;
                case 5: m0[5] += fa[s]; m1[5] += fb[s]; break;
                case 6: m0[6] += fa[s]; m1[6] += fb[s]; break;
                case 7: m0[7] += fa[s]; m1[7] += fb[s]; break;
                case 8: m0[8] += fa[s]; m1[8] += fb[s]; break;
            }
        }
    }
    #pragma unroll
    for (int r = 0; r < 9; ++r) {
        const float invc = 1.0f / (float)(cnt[r] > 0 ? cnt[r] : 1);
        m0[r] *= invc; m1[r] *= invc;
    }
    if (!has_bg) { m0[0] = cx0; m1[0] = cx1; }  // row 0 = context_compen

    // ---- M -> LDS (2-way bank aliasing = free) -----------------------------
    #pragma unroll
    for (int r = 0; r < 9; ++r) {
        MM[r * MROW + l]      = m0[r];
        MM[r * MROW + 64 + l] = m1[r];
    }
    __syncthreads();

    // ---- 44 pairs (i,j), 1<=i<=8, 0<=j<=i: lane p dots rows i,j over 128 ch
    float simv = 0.0f; int pi = 0, pj = 0;
    if (l < 44) {
        pi = (int)((sqrtf(8.0f * (float)l + 9.0f) - 1.0f) * 0.5f);
        pj = l - (pi * (pi + 1) / 2 - 1);
        const float* Ri = MM + pi * MROW;
        const float* Rj = MM + pj * MROW;
        float acc = 0.0f;
        #pragma unroll
        for (int q = 0; q < 32; ++q) {
            float4 x = *(const float4*)(Ri + 4 * q);
            float4 y = *(const float4*)(Rj + 4 * q);
            acc += x.x * y.x + x.y * y.y + x.z * y.z + x.w * y.w;
        }
        simv = acc * 5.0f;                      // 1/T
    }
    if (l < 44) {
        SIMM[pi * 9 + pj] = simv;
        if (pi != pj) SIMM[pj * 9 + pi] = simv;
    }
    __syncthreads();

    // ---- masked logsumexp per present fg row (lane r = row r) --------------
    float li_val = 0.0f;
    if (l >= 1 && l < 9 && ((pm >> l) & 1)) {
        float srow[9];
        #pragma unroll
        for (int j = 0; j < 9; ++j) srow[j] = SIMM[l * 9 + j];
        float vmax = srow[0];                   // col 0 (bg/ctx) always valid
        #pragma unroll
        for (int j = 1; j < 9; ++j)
            if ((pm >> j) & 1) vmax = fmaxf(vmax, srow[j]);
        float se = __expf(srow[0] - vmax);
        #pragma unroll
        for (int j = 1; j < 9; ++j)
            if ((pm >> j) & 1) se += __expf(srow[j] - vmax);
        li_val = vmax + __logf(se) - srow[l];
    }

    // ---- sum li over lanes 1..8; single float2 store -----------------------
    float ssum = li_val;
    #pragma unroll
    for (int off = 8; off >= 1; off >>= 1) ssum += __shfl_down(ssum, off);
    if (l == 0) {
        float2 r;
        r.x = ssum / (float)(fg_count > 0 ? fg_count : 1);  // gl*gv
        r.y = (fg_count > 0) ? 1.0f : 0.0f;                 // gv
        ws[g] = r;
    }
}

// Deterministic 8192 -> 1 reduction
__global__ __launch_bounds__(1024) void reduce_kernel(
    const float2* __restrict__ ws, float* __restrict__ out)
{
    __shared__ float sa[1024], sb[1024];
    const int t = threadIdx.x;
    float a = 0.0f, b2 = 0.0f;
    for (int g = t; g < GQ; g += 1024) {
        float2 v = ws[g];
        a += v.x; b2 += v.y;
    }
    sa[t] = a; sb[t] = b2;
    __syncthreads();
    for (int off = 512; off > 0; off >>= 1) {
        if (t < off) { sa[t] += sa[t + off]; sb[t] += sb[t + off]; }
        __syncthreads();
    }
    if (t == 0) out[0] = 0.1f * (sa[0] / sb[0]);
}

extern "C" void kernel_launch(void* const* d_in, const int* in_sizes, int n_in,
                              void* d_out, int out_size, void* d_ws, size_t ws_size,
                              hipStream_t stream) {
    const int*   labs  = (const int*)d_in[0];    // proposal_instance_mask
    const float* feats = (const float*)d_in[1];  // grouped_features
    const int*   idxs  = (const int*)d_in[2];    // grouped_indices
    const float* ctx   = (const float*)d_in[3];  // context_compen
    float* out = (float*)d_out;
    float2* ws = (float2*)d_ws;

    group_loss_kernel<<<GQ / WPB, 64 * WPB, 0, stream>>>(labs, feats, idxs, ctx, ws);
    reduce_kernel<<<1, 1024, 0, stream>>>(ws, out);
}